// Round 6
// baseline (512.305 us; speedup 1.0000x reference)
//
#include <hip/hip_runtime.h>

constexpr int Bn = 8;
constexpr int Ln = 4096;
constexpr int Dn = 768;
constexpr int NCH = 128;             // chunks per batch for partial colsum
constexpr int RPC = Ln / NCH;        // 32 rows per chunk

typedef float f4 __attribute__((ext_vector_type(4)));

// ---------------------------------------------------------------------------
// K1: partial column sums (no atomics). grid = Bn*NCH = 1024 blocks x 192 thr.
// Each block streams a contiguous 96 KB region (32 rows); part[chunk][d4].
// ---------------------------------------------------------------------------
__global__ void k_colsum_part(const float* __restrict__ x, f4* __restrict__ part) {
    int b = blockIdx.x >> 7;             // / NCH
    int c = blockIdx.x & (NCH - 1);
    int t = threadIdx.x;                 // 0..191 (D/4 = 192)
    const f4* xb = (const f4*)(x + ((size_t)b * Ln + (size_t)c * RPC) * Dn);
    f4 s = {0.f, 0.f, 0.f, 0.f};
    #pragma unroll 8
    for (int l = 0; l < RPC; ++l) {
        s += xb[(size_t)l * (Dn / 4) + t];
    }
    part[(size_t)blockIdx.x * (Dn / 4) + t] = s;
}

// ---------------------------------------------------------------------------
// K2: fused fold + scale + rowdot + epilogue.
// Preamble (per wave, no LDS/sync): fold the 128 chunk-partials of batch b
// into colsum fragments (lane owns f4-columns lane, lane+64, lane+128 -> the
// single wave covers all 768 columns), butterfly ssq, build pre-scaled
//   m[d] = colsum[d] * ||colsum||^2 / (L^4 D^2)    in registers.
// Stream: one wave per row; out = alpha[l] + (x_row . m) * x_row,
// nontemporal stores so the write stream doesn't evict x from L2/L3.
// Derivation: y_l = x_l.colsum/(LD); sum_y = ||colsum||^2/(LD);
//             coef_l = y_l*sum_y/L^2 = x_l . m.
// ---------------------------------------------------------------------------
__global__ void __launch_bounds__(256)
k_fused(const float* __restrict__ x, const float* __restrict__ part,
        const float* __restrict__ alpha, float* __restrict__ out) {
    int wave = threadIdx.x >> 6;
    int lane = threadIdx.x & 63;
    int row  = blockIdx.x * 4 + wave;    // [0, B*L)
    int b    = row >> 12;
    int l    = row & (Ln - 1);

    // ---- preamble: fold partials (L2/L3-hot, 6 KB per wave) ----
    const f4* pb = (const f4*)part + (size_t)b * NCH * (Dn / 4);
    f4 s0 = {0.f,0.f,0.f,0.f}, s1 = {0.f,0.f,0.f,0.f}, s2 = {0.f,0.f,0.f,0.f};
    #pragma unroll 8
    for (int c = 0; c < NCH; ++c) {
        const f4* pr = pb + (size_t)c * (Dn / 4);
        s0 += pr[lane];
        s1 += pr[lane + 64];
        s2 += pr[lane + 128];
    }
    f4 q = s0 * s0 + s1 * s1 + s2 * s2;
    float ssq = q.x + q.y + q.z + q.w;
    #pragma unroll
    for (int off = 1; off < 64; off <<= 1) ssq += __shfl_xor(ssq, off);

    const float f1 = 1.0f / ((float)Ln * (float)Dn);
    float scale = ssq * f1 * f1 / ((float)Ln * (float)Ln);
    f4 m0 = s0 * scale, m1 = s1 * scale, m2 = s2 * scale;

    // ---- stream: dot + epilogue for this wave's row ----
    const f4* xr = (const f4*)(x + (size_t)row * Dn);
    f4 x0 = xr[lane], x1 = xr[lane + 64], x2 = xr[lane + 128];

    f4 p = x0 * m0 + x1 * m1 + x2 * m2;
    float acc = p.x + p.y + p.z + p.w;
    #pragma unroll
    for (int off = 1; off < 64; off <<= 1) acc += __shfl_xor(acc, off);

    float a = alpha[l];
    f4* orow = (f4*)(out + (size_t)row * Dn);
    f4 o0 = a + acc * x0;
    f4 o1 = a + acc * x1;
    f4 o2 = a + acc * x2;
    __builtin_nontemporal_store(o0, &orow[lane]);
    __builtin_nontemporal_store(o1, &orow[lane + 64]);
    __builtin_nontemporal_store(o2, &orow[lane + 128]);
}

// ---------------------------------------------------------------------------
extern "C" void kernel_launch(void* const* d_in, const int* in_sizes, int n_in,
                              void* d_out, int out_size, void* d_ws, size_t ws_size,
                              hipStream_t stream) {
    const float* x     = (const float*)d_in[0];   // [B, L, D]
    const float* alpha = (const float*)d_in[1];   // [L, 1]
    float* out = (float*)d_out;                   // [B, L, D]

    float* part = (float*)d_ws;                   // [Bn*NCH, Dn] ~3.1 MB

    k_colsum_part<<<Bn * NCH, 192, 0, stream>>>(x, (f4*)part);
    k_fused<<<(Bn * Ln) / 4, 256, 0, stream>>>(x, part, alpha, out);
}

// Round 7
// 309.526 us; speedup vs baseline: 1.6551x; 1.6551x over previous
//
#include <hip/hip_runtime.h>

constexpr int Bn = 8;
constexpr int Ln = 4096;
constexpr int Dn = 768;
constexpr int NCH = 128;             // chunk-blocks per batch for partial colsum
constexpr int RPC = Ln / NCH;        // 32 rows per chunk

typedef float f4 __attribute__((ext_vector_type(4)));

// ---------------------------------------------------------------------------
// K1: partial column sums + last-block-per-batch fold (no separate k_scale).
// grid = Bn*NCH = 1024 blocks x 192 threads. Each block streams 32 rows
// (96 KB contiguous) into a per-block partial. Then the LAST block of each
// batch (per-batch atomic counter) folds the 128 partials into colsum and
// writes the pre-scaled vector
//   m[b,d] = colsum[b,d] * ||colsum_b||^2 / (L^4 D^2)
// Derivation: y_l = x_l.colsum/(LD); sum_y = ||colsum||^2/(LD);
//             coef_l = y_l*sum_y/L^2 = x_l . m.
// ---------------------------------------------------------------------------
__global__ void __launch_bounds__(192)
k_colsum_fold(const float* __restrict__ x, f4* __restrict__ part,
              f4* __restrict__ m, int* __restrict__ cnt) {
    int b = blockIdx.x >> 7;             // / NCH
    int c = blockIdx.x & (NCH - 1);
    int t = threadIdx.x;                 // 0..191 (D/4 = 192)
    int wave = t >> 6, lane = t & 63;

    const f4* xb = (const f4*)(x + ((size_t)b * Ln + (size_t)c * RPC) * Dn);
    f4 s = {0.f, 0.f, 0.f, 0.f};
    #pragma unroll 8
    for (int l = 0; l < RPC; ++l) {
        s += xb[(size_t)l * (Dn / 4) + t];
    }
    part[(size_t)blockIdx.x * (Dn / 4) + t] = s;

    // ---- last-block-done handshake (CUB threadFenceReduction pattern) ----
    __shared__ int lastflag;
    __threadfence();                     // make this block's partial visible
    __syncthreads();                     // all threads fenced before the bump
    if (t == 0) {
        int old = atomicAdd(&cnt[b], 1);
        lastflag = (old == NCH - 1);
    }
    __syncthreads();
    if (!lastflag) return;

    // ---- fold: this block is the last of batch b; all partials visible ----
    __threadfence();                     // acquire side
    const f4* pb = part + (size_t)b * NCH * (Dn / 4);
    f4 cs = {0.f, 0.f, 0.f, 0.f};
    #pragma unroll 8
    for (int k = 0; k < NCH; ++k) {
        cs += pb[(size_t)k * (Dn / 4) + t];
    }
    f4 q = cs * cs;
    float ssq = q.x + q.y + q.z + q.w;
    #pragma unroll
    for (int off = 1; off < 64; off <<= 1) ssq += __shfl_xor(ssq, off);
    __shared__ float wsum[3];
    if (lane == 0) wsum[wave] = ssq;
    __syncthreads();
    float ss = wsum[0] + wsum[1] + wsum[2];

    const float f1 = 1.0f / ((float)Ln * (float)Dn);
    float scale = ss * f1 * f1 / ((float)Ln * (float)Ln);
    m[(size_t)b * (Dn / 4) + t] = cs * scale;
}

// ---------------------------------------------------------------------------
// K2: fused rowdot + epilogue (identical to the proven R4 version).
// One wave per row, 4 waves/block, 2048 blocks (32 waves/CU). x held in
// registers for both dot and write-back; NT stores keep the write stream
// from evicting x in L2/L3.
// ---------------------------------------------------------------------------
__global__ void __launch_bounds__(256)
k_fused(const float* __restrict__ x, const f4* __restrict__ m,
        const float* __restrict__ alpha, float* __restrict__ out) {
    int wave = threadIdx.x >> 6;
    int lane = threadIdx.x & 63;
    int row  = blockIdx.x * 4 + wave;    // [0, B*L)
    int b    = row >> 12;
    int l    = row & (Ln - 1);

    const f4* xr = (const f4*)(x + (size_t)row * Dn);
    const f4* mr = m + (size_t)b * (Dn / 4);

    f4 x0 = xr[lane], x1 = xr[lane + 64], x2 = xr[lane + 128];
    f4 m0 = mr[lane], m1 = mr[lane + 64], m2 = mr[lane + 128];

    f4 p = x0 * m0 + x1 * m1 + x2 * m2;
    float acc = p.x + p.y + p.z + p.w;
    #pragma unroll
    for (int off = 1; off < 64; off <<= 1) acc += __shfl_xor(acc, off);

    float a = alpha[l];
    f4* orow = (f4*)(out + (size_t)row * Dn);
    f4 o0 = a + acc * x0;
    f4 o1 = a + acc * x1;
    f4 o2 = a + acc * x2;
    __builtin_nontemporal_store(o0, &orow[lane]);
    __builtin_nontemporal_store(o1, &orow[lane + 64]);
    __builtin_nontemporal_store(o2, &orow[lane + 128]);
}

// ---------------------------------------------------------------------------
extern "C" void kernel_launch(void* const* d_in, const int* in_sizes, int n_in,
                              void* d_out, int out_size, void* d_ws, size_t ws_size,
                              hipStream_t stream) {
    const float* x     = (const float*)d_in[0];   // [B, L, D]
    const float* alpha = (const float*)d_in[1];   // [L, 1]
    float* out = (float*)d_out;                   // [B, L, D]

    // ws layout: part[1024*768 floats = 3 MB] | m[8*768 floats] | cnt[8 ints]
    f4*  part = (f4*)d_ws;
    f4*  m    = part + (size_t)Bn * NCH * (Dn / 4);
    int* cnt  = (int*)(m + (size_t)Bn * (Dn / 4));

    hipMemsetAsync(cnt, 0, Bn * sizeof(int), stream);
    k_colsum_fold<<<Bn * NCH, 192, 0, stream>>>(x, part, m, cnt);
    k_fused<<<(Bn * Ln) / 4, 256, 0, stream>>>(x, m, alpha, out);
}